// Round 4
// baseline (3564.359 us; speedup 1.0000x reference)
//
#include <hip/hip_runtime.h>
#include <cstdint>
#include <cstddef>

// RWKV-7 Tmix forward, MI355X gfx950 — ROUND 4: clean-room fp32-pure oracle.
// No bf16, no MFMA, no transposes, no shuffles: isolates semantics.
// B=2 T=1024 C=2048 H=32 N=64. Workspace high-water: 100608 KiB (~98.3 MiB).

#define DI __device__ __forceinline__
static constexpr int T_ = 1024, C_ = 2048, H_ = 32;

DI float sig_(float z) { return 1.0f / (1.0f + expf(-z)); }

// ---------------- unified oracle GEMM: C[M=2048,N] = act(A)[M,K] @ W[K,N] ----------------
// If mixv != null, A is built on the fly: A[m,k] = x[m,k] + (xprev[m,k]-x[m,k])*mixv[k]
// (token shift; xprev = shift_state row at t==0). Else A read directly with optional
// activation aact (1=tanh, 2=sigmoid). Epilogue epi: 1 -> sigmoid(bias+v),
// 2 -> e^-0.5*sigmoid(bias+v)  [== exp(-softplus(-(bias+v)) - 0.5)].
struct Job {
  const float* A; const float* W; float* C; const float* bias;
  const float* mixv; const float* x; const float* shift;
  int N, K, ntn, aact, epi, tile_end;
};
struct Jobs { Job j[7]; };

__global__ __launch_bounds__(256) void gemm_oracle(Jobs P) {
  __shared__ float As[64][33];
  __shared__ float Ws[32][65];
  int bx = blockIdx.x, ji = 0;
  while (bx >= P.j[ji].tile_end) ++ji;
  Job J = P.j[ji];
  int tix = bx - (ji ? P.j[ji - 1].tile_end : 0);
  int mt = tix / J.ntn, nt = tix % J.ntn;
  int m0 = mt * 64, n0 = nt * 64;
  int tid = threadIdx.x, tx = tid & 15, ty = tid >> 4;
  float acc[4][4] = {};
  for (int k0 = 0; k0 < J.K; k0 += 32) {
    #pragma unroll
    for (int p = 0; p < 8; ++p) {                  // A tile: 64 rows x 32 k
      int idx = p * 256 + tid;
      int r = idx >> 5, kc = idx & 31;
      int m = m0 + r, k = k0 + kc;
      float a;
      if (J.mixv) {
        float xv = J.x[(size_t)m * C_ + k];
        int t = m & (T_ - 1);
        float xp = (t == 0) ? J.shift[(size_t)(m >> 10) * C_ + k]
                            : J.x[(size_t)(m - 1) * C_ + k];
        a = xv + (xp - xv) * J.mixv[k];
      } else {
        a = J.A[(size_t)m * J.K + k];
        if (J.aact == 1) a = tanhf(a);
        else if (J.aact == 2) a = sig_(a);
      }
      As[r][kc] = a;
    }
    #pragma unroll
    for (int p = 0; p < 8; ++p) {                  // W tile: 32 k x 64 n
      int idx = p * 256 + tid;
      int kr = idx >> 6, nc = idx & 63;
      int n = n0 + nc;
      Ws[kr][nc] = (n < J.N) ? J.W[(size_t)(k0 + kr) * J.N + n] : 0.0f;
    }
    __syncthreads();
    #pragma unroll 4
    for (int kc = 0; kc < 32; ++kc) {
      float av[4], bv[4];
      #pragma unroll
      for (int i = 0; i < 4; ++i) av[i] = As[ty * 4 + i][kc];
      #pragma unroll
      for (int jn = 0; jn < 4; ++jn) bv[jn] = Ws[kc][tx * 4 + jn];
      #pragma unroll
      for (int i = 0; i < 4; ++i)
        #pragma unroll
        for (int jn = 0; jn < 4; ++jn) acc[i][jn] += av[i] * bv[jn];
    }
    __syncthreads();
  }
  #pragma unroll
  for (int i = 0; i < 4; ++i) {
    int rw = m0 + ty * 4 + i;
    #pragma unroll
    for (int jn = 0; jn < 4; ++jn) {
      int col = n0 + tx * 4 + jn;
      if (col < J.N) {
        float v = acc[i][jn];
        if (J.epi == 1) v = sig_(J.bias[col] + v);
        else if (J.epi == 2) v = 0.60653065971263342f * sig_(J.bias[col] + v);
        J.C[(size_t)rw * J.N + col] = v;
      }
    }
  }
}

// ---------------- prescan: one block per (b,t,h); LDS tree reduction ----------------
// In-place (same-element, same-thread): k -> k2, v -> v', amat -> a_in, vmix -> b_in.
__global__ __launch_bounds__(64) void prescan(
    float* __restrict__ kio, float* __restrict__ vio,
    float* __restrict__ amat_ain, float* __restrict__ vmix_bin,
    const float* __restrict__ vfirst,
    const float* __restrict__ k_k, const float* __restrict__ k_a) {
  __shared__ float red[64];
  int bid = blockIdx.x, tid = threadIdx.x;
  int h = bid & (H_ - 1);
  size_t base = (size_t)bid * 64 + tid;      // [B,T,H,N] flat
  int cc = h * 64 + tid;
  float kv = kio[base];
  float kkv = kv * k_k[cc];
  red[tid] = kkv * kkv;
  __syncthreads();
  for (int s = 32; s > 0; s >>= 1) { if (tid < s) red[tid] += red[tid + s]; __syncthreads(); }
  float nrm = fmaxf(sqrtf(red[0]), 1e-12f);
  float kkn = kkv / nrm;
  float av = amat_ain[base];
  float vmv = vmix_bin[base];
  float vv = vio[base];
  kio[base] = kv * (1.0f + (av - 1.0f) * k_a[cc]);
  vio[base] = vv + (vfirst[base] - vv) * vmv;
  amat_ain[base] = -kkn;
  vmix_bin[base] = kkn * av;
}

// ---------------- scan: one block per (b,h); thread v holds S[v][0..63] in regs ----------------
__global__ __launch_bounds__(64) void wkv_scan(
    const float* __restrict__ r, const float* __restrict__ k2,
    const float* __restrict__ w, const float* __restrict__ ain,
    const float* __restrict__ bin, const float* __restrict__ vp,
    const float* __restrict__ s0, float* __restrict__ o) {
  __shared__ float rr[64], kk[64], ww[64], aa[64], bb[64];
  int bid = blockIdx.x, v = threadIdx.x;
  int b = bid >> 5, h = bid & 31;
  float S[64];
  {
    const float* sp = s0 + ((size_t)bid * 64 + v) * 64;   // wkv_state[b,h,v,:]
    #pragma unroll
    for (int k = 0; k < 64; ++k) S[k] = sp[k];
  }
  for (int t = 0; t < T_; ++t) {
    size_t a_ = (((size_t)(b * T_ + t)) * H_ + h) * 64;
    rr[v] = r[a_ + v]; kk[v] = k2[a_ + v]; ww[v] = w[a_ + v];
    aa[v] = ain[a_ + v]; bb[v] = bin[a_ + v];
    float vt = vp[a_ + v];
    __syncthreads();
    float sa = 0.f;
    #pragma unroll
    for (int k = 0; k < 64; ++k) sa += S[k] * aa[k];
    float y = 0.f;
    #pragma unroll
    for (int k = 0; k < 64; ++k) {
      S[k] = S[k] * ww[k] + vt * kk[k] + sa * bb[k];
      y += S[k] * rr[k];
    }
    o[a_ + v] = y;          // o aliases ain: ain[t] already staged into aa this step
    __syncthreads();
  }
}

// ---------------- post: GroupNorm + bonus + gate; one block per (b,t,h) ----------------
__global__ __launch_bounds__(64) void post(
    const float* __restrict__ o, const float* __restrict__ r,
    const float* __restrict__ k2, const float* __restrict__ vp,
    const float* __restrict__ g, const float* __restrict__ r_k,
    const float* __restrict__ lnw, const float* __restrict__ lnb,
    float* __restrict__ afin) {
  __shared__ float red[64];
  int bid = blockIdx.x, tid = threadIdx.x;
  int h = bid & 31;
  size_t base = (size_t)bid * 64 + tid;
  int cc = h * 64 + tid;
  float ov = o[base];
  red[tid] = ov; __syncthreads();
  for (int s = 32; s > 0; s >>= 1) { if (tid < s) red[tid] += red[tid + s]; __syncthreads(); }
  float mu = red[0] * (1.0f / 64.0f);
  __syncthreads();
  float dv = ov - mu;
  red[tid] = dv * dv; __syncthreads();
  for (int s = 32; s > 0; s >>= 1) { if (tid < s) red[tid] += red[tid + s]; __syncthreads(); }
  float var = red[0] * (1.0f / 64.0f);
  __syncthreads();
  float on = dv * rsqrtf(var + 6.4e-4f) * lnw[cc] + lnb[cc];   // EPS = 1e-5*8^2
  float pr = r[base] * k2[base] * r_k[cc];
  red[tid] = pr; __syncthreads();
  for (int s = 32; s > 0; s >>= 1) { if (tid < s) red[tid] += red[tid + s]; __syncthreads(); }
  float dot = red[0];
  float val = (on + dot * vp[base]) * g[base];   // g is [B,T,C] flat == same index
  afin[base] = val;
}

// ---------------- host ----------------
static constexpr size_t KB = 1024;
// fp32 [B,T,C] buffers are 16384 KiB each.
static constexpr size_t O_R    = 0;        // [G1 -> post]
static constexpr size_t O_K    = 16384;    // k [G1], k2 in-place [prescan -> post]
static constexpr size_t O_V    = 32768;    // v [G1], v' in-place [prescan -> post]
static constexpr size_t O_WDEC = 49152;    // [G2 -> scan]
static constexpr size_t O_AMAT = 65536;    // amat [G2] -> ain [prescan] -> o [scan -> post]
static constexpr size_t O_VMIX = 81920;    // vmix [G2] -> bin [prescan] -> afin [post -> G3]
static constexpr size_t O_HW   = 98304;    // 2048x64  fp32 = 512 KiB
static constexpr size_t O_HA   = 98816;    // 512 KiB
static constexpr size_t O_HV   = 99328;    // 2048x32 = 256 KiB
static constexpr size_t O_HG   = 99584;    // 2048x128 = 1024 KiB -> end 100608 KiB
static constexpr size_t O_AIN  = O_AMAT;
static constexpr size_t O_O    = O_AMAT;
static constexpr size_t O_BIN  = O_VMIX;
static constexpr size_t O_AFIN = O_VMIX;

extern "C" void kernel_launch(void* const* d_in, const int* in_sizes, int n_in,
                              void* d_out, int out_size, void* d_ws, size_t ws_size,
                              hipStream_t stream) {
  const float* x      = (const float*)d_in[0];
  const float* vfirst = (const float*)d_in[1];
  const float* shift  = (const float*)d_in[2];
  const float* wkv0   = (const float*)d_in[3];
  const float* x_r = (const float*)d_in[4];
  const float* x_w = (const float*)d_in[5];
  const float* x_k = (const float*)d_in[6];
  const float* x_v = (const float*)d_in[7];
  const float* x_a = (const float*)d_in[8];
  const float* x_g = (const float*)d_in[9];
  const float* w0 = (const float*)d_in[10];
  const float* w1 = (const float*)d_in[11];
  const float* w2 = (const float*)d_in[12];
  const float* a0 = (const float*)d_in[13];
  const float* a1 = (const float*)d_in[14];
  const float* a2 = (const float*)d_in[15];
  const float* v0 = (const float*)d_in[16];
  const float* v1 = (const float*)d_in[17];
  const float* v2 = (const float*)d_in[18];
  const float* g1 = (const float*)d_in[19];
  const float* g2 = (const float*)d_in[20];
  const float* k_k = (const float*)d_in[21];
  const float* k_a = (const float*)d_in[22];
  const float* r_k = (const float*)d_in[23];
  const float* W_r = (const float*)d_in[24];
  const float* W_k = (const float*)d_in[25];
  const float* W_v = (const float*)d_in[26];
  const float* W_o = (const float*)d_in[27];
  const float* ln_w = (const float*)d_in[28];
  const float* ln_b = (const float*)d_in[29];

  char* ws = (char*)d_ws;
  auto F = [&](size_t kb) { return (float*)(ws + kb * KB); };
  float* outp = (float*)d_out;

  // G1: token-shift mixes fused into A-load; r, k, v + 4 LoRA-down projections.
  {
    Jobs G{};
    int cum = 0, i = 0;
    auto add = [&](const float* W, float* C, const float* mixv, int N) {
      int ntn = (N + 63) / 64;
      cum += 32 * ntn;
      G.j[i++] = Job{nullptr, W, C, nullptr, mixv, x, shift, N, 2048, ntn, 0, 0, cum};
    };
    add(W_r, F(O_R), x_r, 2048);
    add(W_k, F(O_K), x_k, 2048);
    add(W_v, F(O_V), x_v, 2048);
    add(w1, F(O_HW), x_w, 64);
    add(a1, F(O_HA), x_a, 64);
    add(v1, F(O_HV), x_v, 32);
    add(g1, F(O_HG), x_g, 128);
    gemm_oracle<<<dim3(cum), dim3(256), 0, stream>>>(G);
  }

  // G2: LoRA-up with fused input activations and epilogues.
  {
    Jobs G{};
    int cum = 0, i = 0;
    auto add = [&](const float* A, const float* W, float* C, const float* bias,
                   int K, int aact, int epi) {
      cum += 32 * 32;
      G.j[i++] = Job{A, W, C, bias, nullptr, nullptr, nullptr, 2048, K, 32, aact, epi, cum};
    };
    add(F(O_HW), w2, F(O_WDEC), w0, 64, 1, 2);   // w = e^-0.5*sigmoid(w0 + tanh(hw)@w2)
    add(F(O_HA), a2, F(O_AMAT), a0, 64, 0, 1);   // a = sigmoid(a0 + ha@a2)
    add(F(O_HV), v2, F(O_VMIX), v0, 32, 0, 1);   // vmix = sigmoid(v0 + hv@v2)
    add(F(O_HG), g2, outp,     nullptr, 128, 2, 0); // g = sigmoid(hg)@g2  (lives in d_out)
    gemm_oracle<<<dim3(cum), dim3(256), 0, stream>>>(G);
  }

  // prescan: kk-norm; k->k2, v->v', amat->a_in, vmix->b_in (all same-element in-place).
  prescan<<<dim3(65536), dim3(64), 0, stream>>>(F(O_K), F(O_V), F(O_AMAT), F(O_VMIX),
                                                vfirst, k_k, k_a);

  // scan: 64 blocks (b,h), S in registers, o overwrites ain region (safe per-step).
  wkv_scan<<<dim3(64), dim3(64), 0, stream>>>(F(O_R), F(O_K), F(O_WDEC), F(O_AIN),
                                              F(O_BIN), F(O_V), wkv0, F(O_O));

  // post: GroupNorm + bonus + gate -> afin (over bin region, dead after scan).
  post<<<dim3(65536), dim3(64), 0, stream>>>(F(O_O), F(O_R), F(O_K), F(O_V),
                                             outp, r_k, ln_w, ln_b, F(O_AFIN));

  // G3: out = afin @ W_o  (overwrites g in d_out; g already consumed by post).
  {
    Jobs G{};
    G.j[0] = Job{F(O_AFIN), W_o, outp, nullptr, nullptr, nullptr, nullptr,
                 2048, 2048, 32, 0, 0, 1024};
    gemm_oracle<<<dim3(1024), dim3(256), 0, stream>>>(G);
  }

  (void)in_sizes; (void)n_in; (void)out_size; (void)ws_size;
}